// Round 6
// baseline (776.917 us; speedup 1.0000x reference)
//
#include <hip/hip_runtime.h>

typedef _Float16 v8h __attribute__((ext_vector_type(8)));
typedef float    v4f __attribute__((ext_vector_type(4)));

template<int V> struct IC { static constexpr int value = V; };

__device__ __forceinline__ float fast_tanh(float x) {
    float e = __expf(2.0f * x);
    return 1.0f - 2.0f / (e + 1.0f);
}

// ---------------------------------------------------------------------------
// pack layout (halves), same as validated rounds 2-5:
//  hidden: idx = ((((pipe*3+l)*8 + nt)*4 + kk)*64 + lane)*8 + j     [0, 98304)
//          value = Wh[l][k = kk*32 + (lane>>4)*8 + j][n = nt*16 + (lane&15)]
//  L0:     98304 + ((pipe*8 + nt)*64 + lane)*8 + j                  [98304, 106496)
//          value = Win[k = (lane>>4)*8+j][n] for k < in_dim else 0
// ---------------------------------------------------------------------------
__global__ void pack_weights(const float* __restrict__ dpWh,
                             const float* __restrict__ icWh,
                             const float* __restrict__ dpWin,
                             const float* __restrict__ icWin,
                             _Float16* __restrict__ out) {
    int idx = blockIdx.x * 256 + threadIdx.x;
    if (idx < 98304) {
        int j    = idx & 7;
        int lane = (idx >> 3) & 63;
        int kk   = (idx >> 9) & 3;
        int nt   = (idx >> 11) & 7;
        int lp   = idx >> 14;           // 0..5
        int l    = lp % 3;
        const float* src = (lp >= 3) ? icWh : dpWh;
        int k = kk * 32 + (lane >> 4) * 8 + j;
        int n = nt * 16 + (lane & 15);
        out[idx] = (_Float16)src[(l * 128 + k) * 128 + n];
    } else if (idx < 106496) {
        int f    = idx - 98304;
        int j    = f & 7;
        int lane = (f >> 3) & 63;
        int nt   = (f >> 9) & 7;
        int pipe = (f >> 12) & 1;
        int k = (lane >> 4) * 8 + j;
        int n = nt * 16 + (lane & 15);
        float v = 0.0f;
        if (pipe == 0) { if (k < 4) v = dpWin[k * 128 + n]; }
        else           { if (k < 3) v = icWin[k * 128 + n]; }
        out[idx] = (_Float16)v;
    }
}

// LDS (dynamic, 142144 B -> 1 block/CU of 1024 threads = 16 waves = 4/SIMD):
//   [0,      69632)  act0 : 256 rows x 136 halves (row = set*64 + phys*4 + stream)
//   [69632, 139264)  act1 : ping-pong partner
//   [139264,140288)  woutb: f32[2][128]
//   [140288,141312)  cbuf : f32[256] per-virtual-row scalar outputs
//   [141312,142144)  rowb : f32[16][13] geometry terms for the combine phase
#define ROWH 136
#define ABUFH (256 * ROWH)
#define SMEM_BYTES 142144

__launch_bounds__(1024, 4)
__global__ void node_main(const float* __restrict__ tx,
                          const float* __restrict__ dpBin, const float* __restrict__ dpBh,
                          const float* __restrict__ dpWout, const float* __restrict__ dpBout,
                          const float* __restrict__ icBin, const float* __restrict__ icBh,
                          const float* __restrict__ icWout, const float* __restrict__ icBout,
                          const _Float16* __restrict__ pack,
                          float* __restrict__ outPot, float* __restrict__ outAcc,
                          int N)
{
    extern __shared__ char smem[];
    _Float16* act0 = (_Float16*)smem;
    _Float16* act1 = act0 + ABUFH;
    float* woutb = (float*)(smem + 139264);
    float* cbuf  = (float*)(smem + 140288);
    float* rowb  = (float*)(smem + 141312);

    const int tid  = threadIdx.x;
    const int wave = tid >> 6;          // 0..15
    const int lane = tid & 63;
    const int l15  = lane & 15;
    const int s    = lane >> 4;
    const int h    = wave >> 3;         // half: tiles h*8 .. h*8+7
    const int cs   = wave & 7;          // my 16-column slice
    const int col  = cs * 16 + l15;

    if (tid < 128) {
        woutb[tid]       = dpWout[tid];
        woutb[128 + tid] = icWout[tid];
    }

    // ---- persistent weights: my cs-slice of all 6 hidden layers (96 VGPR) ----
    v8h wreg[6][4];
    #pragma unroll
    for (int L = 0; L < 6; L++)
        #pragma unroll
        for (int kk = 0; kk < 4; kk++)
            wreg[L][kk] = *(const v8h*)(pack + (((L * 8 + cs) * 4 + kk) << 9) + (lane << 3));

    float biasv[8];   // [0]=dp Bin, [1..3]=dp Bh, [4]=ic Bin, [5..7]=ic Bh (my col)
    biasv[0] = dpBin[col];
    biasv[4] = icBin[col];
    #pragma unroll
    for (int l = 0; l < 3; l++) {
        biasv[1 + l] = dpBh[l * 128 + col];
        biasv[5 + l] = icBh[l * 128 + col];
    }
    const bool icout = (wave >= 12);                   // out-dot tile pipe
    const float boutv = icout ? icBout[0] : dpBout[0];
    __syncthreads();

    // ---- static LDS bases ----
    const int ep_off = s * (4 * ROWH) + col;           // epilogue write base
    const int rd_off = l15 * ROWH + s * 8;             // A-fragment read base
    const int hoff   = h * (128 * ROWH);
    _Float16* ep0 = act0 + hoff + ep_off;
    _Float16* ep1 = act1 + hoff + ep_off;
    const _Float16* rd0 = act0 + hoff + rd_off;
    const _Float16* rd1 = act1 + hoff + rd_off;

    auto epi = [&](v4f v, _Float16* wb, int j) {
        float hh = fast_tanh(v[0]);
        float D = 1.0f - hh * hh;
        _Float16* p = wb + j * (16 * ROWH);
        p[0           ] = (_Float16)hh;
        p[1 * ROWH] = (_Float16)(D * v[1]);
        p[2 * ROWH] = (_Float16)(D * v[2]);
        p[3 * ROWH] = (_Float16)(D * v[3]);
    };

    // one hidden layer: my 8 tiles (j), weights stationary in VGPRs
    auto hpass = [&](auto Lc, const _Float16* rb, _Float16* wb) {
        constexpr int ldp = decltype(Lc)::value;       // dp layer 0..2
        constexpr int lic = ldp + 3;
        const float bdp = biasv[1 + ldp];
        const float bic = biasv[5 + ldp];
        #pragma unroll
        for (int j = 0; j < 8; j++) {
            int ro = j * (16 * ROWH);
            v8h a0 = *(const v8h*)(rb + ro);
            v8h a1 = *(const v8h*)(rb + ro + 32);
            v8h a2 = *(const v8h*)(rb + ro + 64);
            v8h a3 = *(const v8h*)(rb + ro + 96);
            bool dp = (h == 0) || (j < 4);             // tile m = h*8+j < 12 ?
            v4f acc = {dp ? bdp : bic, 0.0f, 0.0f, 0.0f};
            if (dp) {
                acc = __builtin_amdgcn_mfma_f32_16x16x32_f16(a0, wreg[ldp][0], acc, 0, 0, 0);
                acc = __builtin_amdgcn_mfma_f32_16x16x32_f16(a1, wreg[ldp][1], acc, 0, 0, 0);
                acc = __builtin_amdgcn_mfma_f32_16x16x32_f16(a2, wreg[ldp][2], acc, 0, 0, 0);
                acc = __builtin_amdgcn_mfma_f32_16x16x32_f16(a3, wreg[ldp][3], acc, 0, 0, 0);
            } else {
                acc = __builtin_amdgcn_mfma_f32_16x16x32_f16(a0, wreg[lic][0], acc, 0, 0, 0);
                acc = __builtin_amdgcn_mfma_f32_16x16x32_f16(a1, wreg[lic][1], acc, 0, 0, 0);
                acc = __builtin_amdgcn_mfma_f32_16x16x32_f16(a2, wreg[lic][2], acc, 0, 0, 0);
                acc = __builtin_amdgcn_mfma_f32_16x16x32_f16(a3, wreg[lic][3], acc, 0, 0, 0);
            }
            epi(acc, wb, j);
        }
    };

    const float NP0 = 1.0f - 0.7745966692414834f;      // GL node+1
    const float NP2 = 1.0f + 0.7745966692414834f;

    const int nbat = (N + 15) >> 4;
    for (int b = blockIdx.x; b < nbat; b += gridDim.x) {
        // ---- L0 weight prefetch (L2-resident after first batch) ----
        v8h wl0d = *(const v8h*)(pack + 98304 + ((cs * 64 + lane) << 3));
        v8h wl0i = *(const v8h*)(pack + 98304 + (((8 + cs) * 64 + lane) << 3));

        // ---- geometry for phys row lane&15 (base part needed by all waves) ----
        int prow = b * 16 + l15;
        float4 q = (prow < N) ? ((const float4*)tx)[prow] : make_float4(0.f, 1.f, 1.f, 1.f);
        float t = q.x, x = q.y, y = q.z, z = q.w;
        float r2 = x * x + y * y + z * z;
        float r  = sqrtf(r2 + 1e-12f);
        float rinv = 1.0f / r;
        float uc = fminf(1.0f, fmaxf(-1.0f, z * rinv));
        float th = acosf(uc);
        float ph = atan2f(y, x);
        if (wave == 0 && lane < 16) {                  // derivative terms -> LDS
            float rinv3 = rinv * rinv * rinv;
            float dacos = -1.0f / sqrtf(fmaxf(1.0f - uc * uc, 1e-30f));
            float rho2 = fmaxf(x * x + y * y, 1e-30f);
            float opr  = 1.0f + r;
            float den  = r * r + 0.1f;
            float isq  = 1.0f / sqrtf(den);
            float* rb = rowb + lane * 13;
            rb[0]  = t;
            rb[1]  = x * rinv; rb[2] = y * rinv; rb[3] = z * rinv;
            rb[4]  = dacos * (-x * z * rinv3);
            rb[5]  = dacos * (-y * z * rinv3);
            rb[6]  = dacos * (rinv - z * z * rinv3);
            rb[7]  = -y / rho2;
            rb[8]  =  x / rho2;
            rb[9]  = -1.0f / opr;
            rb[10] =  1.0f / (opr * opr);
            rb[11] = -isq;
            rb[12] = r * isq * isq * isq;
        }

        // distribute (t,r,th,ph) of phys p = mt*4 + (l15>>2) to this lane
        float tv[4], rv[4], thv[4], phv[4];
        #pragma unroll
        for (int mt = 0; mt < 4; mt++) {
            int src = mt * 4 + ((lane >> 2) & 3);
            tv[mt]  = __shfl(t,  src);
            rv[mt]  = __shfl(r,  src);
            thv[mt] = __shfl(th, src);
            phv[mt] = __shfl(ph, src);
        }

        // ---- L0: my 8 tiles, K=32 MFMA, seeds built in-register -> act0 ----
        {
            int st = l15 & 3;
            bool p = (st == 0);
            #pragma unroll
            for (int j = 0; j < 8; j++) {
                int set = h * 2 + (j >> 2);            // 0..3; 3 = ic
                int mt  = j & 3;
                bool isic = (set == 3);
                float np1 = (set == 0) ? NP0 : ((set == 1) ? 1.0f : NP2);
                float e0, e1, e2, e3;
                if (isic) {
                    e0 = p ? rv[mt]  : (st == 1 ? 1.0f : 0.0f);
                    e1 = p ? thv[mt] : (st == 2 ? 1.0f : 0.0f);
                    e2 = p ? phv[mt] : (st == 3 ? 1.0f : 0.0f);
                    e3 = 0.0f;
                } else {
                    float ts = 0.5f * tv[mt] * np1;
                    e0 = p ? ts : 0.0f;
                    e1 = p ? rv[mt]  : (st == 1 ? 1.0f : 0.0f);
                    e2 = p ? thv[mt] : (st == 2 ? 1.0f : 0.0f);
                    e3 = p ? phv[mt] : (st == 3 ? 1.0f : 0.0f);
                }
                v8h a = {};
                a[0] = (_Float16)e0; a[1] = (_Float16)e1;
                a[2] = (_Float16)e2; a[3] = (_Float16)e3;
                v8h az = {};
                v8h am = (s == 0) ? a : az;
                v4f acc = {isic ? biasv[4] : biasv[0], 0.0f, 0.0f, 0.0f};
                acc = __builtin_amdgcn_mfma_f32_16x16x32_f16(am, isic ? wl0i : wl0d, acc, 0, 0, 0);
                epi(acc, ep0, j);
            }
        }
        __syncthreads();                               // bar1: act0 ready

        hpass(IC<0>{}, rd0, ep1);                      // h1: act0 -> act1
        __syncthreads();                               // bar2
        hpass(IC<1>{}, rd1, ep0);                      // h2: act1 -> act0
        __syncthreads();                               // bar3
        hpass(IC<2>{}, rd0, ep1);                      // h3: act0 -> act1
        __syncthreads();                               // bar4: act1 final

        // ---- output dot (scalar fp32): tile `wave`, 4 lanes per row ----
        {
            int v = wave * 16 + (lane >> 2);
            const _Float16* rp = act1 + v * ROWH + (lane & 3) * 32;
            const float*    wp = woutb + (icout ? 128 : 0) + (lane & 3) * 32;
            float sum = 0.0f;
            #pragma unroll
            for (int c = 0; c < 4; c++) {
                v8h hv = *(const v8h*)(rp + c * 8);
                v4f w0 = *(const v4f*)(wp + c * 8);
                v4f w1 = *(const v4f*)(wp + c * 8 + 4);
                #pragma unroll
                for (int j = 0; j < 4; j++) {
                    sum += (float)hv[j]     * w0[j];
                    sum += (float)hv[4 + j] * w1[j];
                }
            }
            sum += __shfl_xor(sum, 1);
            sum += __shfl_xor(sum, 2);
            if ((lane & 3) == 0) {
                if (((lane >> 2) & 3) == 0) sum += boutv;   // primal stream bias
                cbuf[v] = sum;
            }
        }
        __syncthreads();                               // bar5: cbuf ready

        // ---- quadrature + envelope + chain rule (wave 0, lanes 0-15) ----
        if (wave == 0 && lane < 16) {
            int row = b * 16 + lane;
            if (row < N) {
                const float* rb = rowb + lane * 13;
                float ah = 0.5f * rb[0];
                float vic = cbuf[192 + lane * 4 + 0];
                float g0  = cbuf[192 + lane * 4 + 1];
                float g1  = cbuf[192 + lane * 4 + 2];
                float g2  = cbuf[192 + lane * 4 + 3];
                float dsum = 0.f, ds0 = 0.f, ds1 = 0.f, ds2 = 0.f;
                const float wq[3] = {0.5555555555555556f, 0.8888888888888889f, 0.5555555555555556f};
                #pragma unroll
                for (int qq = 0; qq < 3; qq++) {
                    float w = wq[qq];
                    dsum += w * cbuf[qq * 64 + lane * 4 + 0];
                    ds0  += w * cbuf[qq * 64 + lane * 4 + 1];
                    ds1  += w * cbuf[qq * 64 + lane * 4 + 2];
                    ds2  += w * cbuf[qq * 64 + lane * 4 + 3];
                }
                float tcv  = vic + ah * dsum;
                float dtc0 = g0 + ah * ds0, dtc1 = g1 + ah * ds1, dtc2 = g2 + ah * ds2;
                float sEnv = rb[9], dsdr = rb[10], Aan = rb[11], dAdr = rb[12];
                float pot = tcv * sEnv + Aan;
                float gx0 = sEnv * dtc0 + tcv * dsdr + dAdr;
                float gx1 = sEnv * dtc1;
                float gx2 = sEnv * dtc2;
                float ax = -(gx0 * rb[1] + gx1 * rb[4] + gx2 * rb[7]);
                float ay = -(gx0 * rb[2] + gx1 * rb[5] + gx2 * rb[8]);
                float az = -(gx0 * rb[3] + gx1 * rb[6]);
                outPot[row] = pot;
                outAcc[row * 3 + 0] = ax;
                outAcc[row * 3 + 1] = ay;
                outAcc[row * 3 + 2] = az;
            }
        }
        __syncthreads();                               // rowb/cbuf safe to reuse
    }
}

extern "C" void kernel_launch(void* const* d_in, const int* in_sizes, int n_in,
                              void* d_out, int out_size, void* d_ws, size_t ws_size,
                              hipStream_t stream) {
    (void)n_in; (void)out_size;
    const float* tx     = (const float*)d_in[0];
    const float* dpWin  = (const float*)d_in[1];
    const float* dpBin  = (const float*)d_in[2];
    const float* dpWh   = (const float*)d_in[3];
    const float* dpBh   = (const float*)d_in[4];
    const float* dpWout = (const float*)d_in[5];
    const float* dpBout = (const float*)d_in[6];
    const float* icWin  = (const float*)d_in[7];
    const float* icBin  = (const float*)d_in[8];
    const float* icWh   = (const float*)d_in[9];
    const float* icBh   = (const float*)d_in[10];
    const float* icWout = (const float*)d_in[11];
    const float* icBout = (const float*)d_in[12];

    int N = in_sizes[0] / 4;
    if (ws_size < (size_t)(106496 * sizeof(_Float16))) return;
    _Float16* pack = (_Float16*)d_ws;
    float* outPot = (float*)d_out;
    float* outAcc = outPot + N;

    pack_weights<<<(106496 + 255) / 256, 256, 0, stream>>>(dpWh, icWh, dpWin, icWin, pack);

    (void)hipFuncSetAttribute(reinterpret_cast<const void*>(node_main),
                              hipFuncAttributeMaxDynamicSharedMemorySize, SMEM_BYTES);
    node_main<<<256, 1024, SMEM_BYTES, stream>>>(tx,
        dpBin, dpBh, dpWout, dpBout,
        icBin, icBh, icWout, icBout,
        pack, outPot, outAcc, N);
}

// Round 8
// 374.753 us; speedup vs baseline: 2.0731x; 2.0731x over previous
//
#include <hip/hip_runtime.h>

typedef _Float16 v8h __attribute__((ext_vector_type(8)));
typedef _Float16 v4h __attribute__((ext_vector_type(4)));
typedef float    v4f __attribute__((ext_vector_type(4)));

template<int V> struct IC { static constexpr int value = V; };

__device__ __forceinline__ float fast_tanh(float x) {
    float e = __expf(2.0f * x);
    return 1.0f - 2.0f / (e + 1.0f);
}

// ---------------------------------------------------------------------------
// pack layout (halves), UNCHANGED from validated rounds 2-6. The fragment is
// role-symmetric: A(m,k) and B(n,k) both map lane(l15,s) -> own=l15, k=s*8+j.
//  hidden: idx = ((((pipe*3+l)*8 + nt)*4 + kk)*64 + lane)*8 + j     [0, 98304)
//          value = Wh[l][k = kk*32 + (lane>>4)*8 + j][n = nt*16 + (lane&15)]
//  L0:     98304 + ((pipe*8 + nt)*64 + lane)*8 + j                  [98304, 106496)
//          value = Win[k = (lane>>4)*8+j][n] for k < in_dim else 0
// ---------------------------------------------------------------------------
__global__ void pack_weights(const float* __restrict__ dpWh,
                             const float* __restrict__ icWh,
                             const float* __restrict__ dpWin,
                             const float* __restrict__ icWin,
                             _Float16* __restrict__ out) {
    int idx = blockIdx.x * 256 + threadIdx.x;
    if (idx < 98304) {
        int j    = idx & 7;
        int lane = (idx >> 3) & 63;
        int kk   = (idx >> 9) & 3;
        int nt   = (idx >> 11) & 7;
        int lp   = idx >> 14;           // 0..5
        int l    = lp % 3;
        const float* src = (lp >= 3) ? icWh : dpWh;
        int k = kk * 32 + (lane >> 4) * 8 + j;
        int n = nt * 16 + (lane & 15);
        out[idx] = (_Float16)src[(l * 128 + k) * 128 + n];
    } else if (idx < 106496) {
        int f    = idx - 98304;
        int j    = f & 7;
        int lane = (f >> 3) & 63;
        int nt   = (f >> 9) & 7;
        int pipe = (f >> 12) & 1;
        int k = (lane >> 4) * 8 + j;
        int n = nt * 16 + (lane & 15);
        float v = 0.0f;
        if (pipe == 0) { if (k < 4) v = dpWin[k * 128 + n]; }
        else           { if (k < 3) v = icWin[k * 128 + n]; }
        out[idx] = (_Float16)v;
    }
}

// LDS (dynamic, 141312 B -> 1 block/CU, 8 waves = 2/SIMD):
//   act layout: act[vrow][feature], vrow = set*64 + stream*16 + phys,
//   row stride ROWH=136 halves (272 B). b64 writes & b128 reads bank-balanced.
//   [0,      69632)  act0
//   [69632, 139264)  act1
//   [139264,140288)  woutb: f32[2][128]
//   [140288,141312)  cbuf : f32[256]
#define ROWH 136
#define ABUFH (256 * ROWH)
#define SMEM_BYTES 141312

__launch_bounds__(512, 2)
__global__ void node_main(const float* __restrict__ tx,
                          const float* __restrict__ dpBin, const float* __restrict__ dpBh,
                          const float* __restrict__ dpWout, const float* __restrict__ dpBout,
                          const float* __restrict__ icBin, const float* __restrict__ icBh,
                          const float* __restrict__ icWout, const float* __restrict__ icBout,
                          const _Float16* __restrict__ pack,
                          float* __restrict__ outPot, float* __restrict__ outAcc,
                          int N)
{
    extern __shared__ char smem[];
    _Float16* act0 = (_Float16*)smem;
    _Float16* act1 = act0 + ABUFH;
    float* woutb = (float*)(smem + 139264);
    float* cbuf  = (float*)(smem + 140288);

    const int tid  = threadIdx.x;
    const int wave = tid >> 6;          // 0..7 = my 16-feature slice cs
    const int lane = tid & 63;
    const int l15  = lane & 15;
    const int s    = lane >> 4;
    const int cs   = wave;

    if (tid < 128) {
        woutb[tid]       = dpWout[tid];
        woutb[128 + tid] = icWout[tid];
    }

    // ---- persistent weights: my cs-slice of all 6 hidden layers (A-operand) ----
    v8h wreg[6][4];
    #pragma unroll
    for (int L = 0; L < 6; L++)
        #pragma unroll
        for (int kk = 0; kk < 4; kk++)
            wreg[L][kk] = *(const v8h*)(pack + (((L * 8 + cs) * 4 + kk) << 9) + (lane << 3));

    // per-thread bias vectors for my 4 output features (rows s*4..s*4+3)
    const int fb = cs * 16 + s * 4;
    v4f bias4[8];   // [0]=dp Bin, [1..3]=dp Bh, [4]=ic Bin, [5..7]=ic Bh
    #pragma unroll
    for (int j = 0; j < 4; j++) {
        bias4[0][j] = dpBin[fb + j];
        bias4[4][j] = icBin[fb + j];
    }
    #pragma unroll
    for (int l = 0; l < 3; l++)
        #pragma unroll
        for (int j = 0; j < 4; j++) {
            bias4[1 + l][j] = dpBh[l * 128 + fb + j];
            bias4[5 + l][j] = icBh[l * 128 + fb + j];
        }
    const float boutd = dpBout[0];
    const float bouti = icBout[0];

    // unit-tangent B-fragments (constants: e_k at k = 0..3)
    v8h efr[4];
    {
        v8h e0 = {}, e1 = {}, e2 = {}, e3 = {};
        if (s == 0) {
            e0[0] = (_Float16)1.0f; e1[1] = (_Float16)1.0f;
            e2[2] = (_Float16)1.0f; e3[3] = (_Float16)1.0f;
        }
        efr[0] = e0; efr[1] = e1; efr[2] = e2; efr[3] = e3;
    }
    __syncthreads();

    // wout A-fragment (row m=0 only): my out-tiles are 2*wave, 2*wave+1
    v8h wof[4];
    {
        const float* wsrc = woutb + ((wave >= 6) ? 128 : 0);
        #pragma unroll
        for (int kk = 0; kk < 4; kk++) {
            v8h w = {};
            if (l15 == 0)
                #pragma unroll
                for (int j = 0; j < 8; j++)
                    w[j] = (_Float16)wsrc[kk * 32 + s * 8 + j];
            wof[kk] = w;
        }
    }

    // ---- static LDS bases ----
    _Float16* ep0 = act0 + l15 * ROWH + cs * 16 + s * 4;   // epilogue writes
    _Float16* ep1 = act1 + l15 * ROWH + cs * 16 + s * 4;
    const _Float16* rd0 = act0 + l15 * ROWH + s * 8;       // B-fragment reads
    const _Float16* rd1 = act1 + l15 * ROWH + s * 8;

    // epilogue: lane holds 4 consecutive features of ONE virtual row
    auto epi_p = [&](v4f acc, v4f& Dk, _Float16* p) {     // primal tile
        float h0 = fast_tanh(acc[0]), h1 = fast_tanh(acc[1]);
        float h2 = fast_tanh(acc[2]), h3 = fast_tanh(acc[3]);
        Dk[0] = 1.0f - h0 * h0; Dk[1] = 1.0f - h1 * h1;
        Dk[2] = 1.0f - h2 * h2; Dk[3] = 1.0f - h3 * h3;
        v4h w = {(_Float16)h0, (_Float16)h1, (_Float16)h2, (_Float16)h3};
        *(v4h*)p = w;
    };
    auto epi_t = [&](v4f acc, const v4f& Dk, _Float16* p) { // tangent tile
        v4h w = {(_Float16)(Dk[0] * acc[0]), (_Float16)(Dk[1] * acc[1]),
                 (_Float16)(Dk[2] * acc[2]), (_Float16)(Dk[3] * acc[3])};
        *(v4h*)p = w;
    };

    // one hidden layer: 16 stream-uniform tiles, weights stationary as A
    auto hpass = [&](auto Lc, const _Float16* rb, _Float16* wb) {
        constexpr int L = decltype(Lc)::value;
        #pragma unroll
        for (int set = 0; set < 4; set++) {
            const bool icp = (set == 3);
            const v8h* W = icp ? wreg[L + 3] : wreg[L];
            v4f Dk;
            #pragma unroll
            for (int st = 0; st < 4; st++) {
                const int ro = (set * 64 + st * 16) * ROWH;
                v8h b0 = *(const v8h*)(rb + ro);
                v8h b1 = *(const v8h*)(rb + ro + 32);
                v8h b2 = *(const v8h*)(rb + ro + 64);
                v8h b3 = *(const v8h*)(rb + ro + 96);
                v4f acc;
                if (st == 0) acc = icp ? bias4[5 + L] : bias4[1 + L];
                else { v4f z = {0.f, 0.f, 0.f, 0.f}; acc = z; }
                acc = __builtin_amdgcn_mfma_f32_16x16x32_f16(W[0], b0, acc, 0, 0, 0);
                acc = __builtin_amdgcn_mfma_f32_16x16x32_f16(W[1], b1, acc, 0, 0, 0);
                acc = __builtin_amdgcn_mfma_f32_16x16x32_f16(W[2], b2, acc, 0, 0, 0);
                acc = __builtin_amdgcn_mfma_f32_16x16x32_f16(W[3], b3, acc, 0, 0, 0);
                _Float16* p = wb + (set * 64 + st * 16) * ROWH;
                if (st == 0) epi_p(acc, Dk, p);
                else         epi_t(acc, Dk, p);
            }
        }
    };

    const float NP0 = 1.0f - 0.7745966692414834f;   // GL node+1
    const float NP2 = 1.0f + 0.7745966692414834f;

    const int nbat = (N + 15) >> 4;
    for (int b = blockIdx.x; b < nbat; b += gridDim.x) {
        // ---- L0 weights (L2/L1-resident after first batch) ----
        v8h wl0d = *(const v8h*)(pack + 98304 + ((cs * 64 + lane) << 3));
        v8h wl0i = *(const v8h*)(pack + 98304 + (((8 + cs) * 64 + lane) << 3));

        // ---- geometry for phys row l15 (per-lane; no shuffles needed) ----
        int prow = b * 16 + l15;
        float4 q = (prow < N) ? ((const float4*)tx)[prow] : make_float4(0.f, 1.f, 1.f, 1.f);
        float t = q.x, x = q.y, y = q.z, z = q.w;
        float r2 = x * x + y * y + z * z;
        float r  = sqrtf(r2 + 1e-12f);
        float rinv = 1.0f / r;
        float uc = fminf(1.0f, fmaxf(-1.0f, z * rinv));
        float th = acosf(uc);
        float ph = atan2f(y, x);
        float rinv3 = rinv * rinv * rinv;
        float dacos = -1.0f / sqrtf(fmaxf(1.0f - uc * uc, 1e-30f));
        float dthx = dacos * (-x * z * rinv3);
        float dthy = dacos * (-y * z * rinv3);
        float dthz = dacos * (rinv - z * z * rinv3);
        float rho2 = fmaxf(x * x + y * y, 1e-30f);
        float dphx = -y / rho2;
        float dphy =  x / rho2;
        float opr  = 1.0f + r;
        float sEnv = -1.0f / opr;
        float dsdr =  1.0f / (opr * opr);
        float den  = r * r + 0.1f;
        float isq  = 1.0f / sqrtf(den);
        float Aan  = -isq;
        float dAdr = r * isq * isq * isq;
        float xr = x * rinv, yr = y * rinv, zr = z * rinv;

        // ---- L0: B-frags from own scalars / constant unit tangents ----
        v8h prim[4];
        {
            v8h z4 = {};
            #pragma unroll
            for (int set = 0; set < 3; set++) {
                float np1 = (set == 0) ? NP0 : ((set == 1) ? 1.0f : NP2);
                float ts = 0.5f * t * np1;
                v8h pm = {};
                pm[0] = (_Float16)ts; pm[1] = (_Float16)r;
                pm[2] = (_Float16)th; pm[3] = (_Float16)ph;
                prim[set] = (s == 0) ? pm : z4;
            }
            v8h pi = {};
            pi[0] = (_Float16)r; pi[1] = (_Float16)th; pi[2] = (_Float16)ph;
            prim[3] = (s == 0) ? pi : z4;
        }
        #pragma unroll
        for (int set = 0; set < 4; set++) {
            const bool icp = (set == 3);
            v8h wf = icp ? wl0i : wl0d;
            v4f Dk;
            #pragma unroll
            for (int st = 0; st < 4; st++) {
                v8h bf;
                if (st == 0) bf = prim[set];
                else         bf = efr[icp ? (st - 1) : st];
                v4f acc;
                if (st == 0) acc = icp ? bias4[4] : bias4[0];
                else { v4f zz = {0.f, 0.f, 0.f, 0.f}; acc = zz; }
                acc = __builtin_amdgcn_mfma_f32_16x16x32_f16(wf, bf, acc, 0, 0, 0);
                _Float16* p = ep0 + (set * 64 + st * 16) * ROWH;
                if (st == 0) epi_p(acc, Dk, p);
                else         epi_t(acc, Dk, p);
            }
        }
        __syncthreads();                               // bar1: act0 ready

        hpass(IC<0>{}, rd0, ep1);                      // h1: act0 -> act1
        __syncthreads();                               // bar2
        hpass(IC<1>{}, rd1, ep0);                      // h2: act1 -> act0
        __syncthreads();                               // bar3
        hpass(IC<2>{}, rd0, ep1);                      // h3: act0 -> act1
        __syncthreads();                               // bar4: act1 final

        // ---- output dot via MFMA (row 0 of D' = results) ----
        #pragma unroll
        for (int tt = 0; tt < 2; tt++) {
            int tname = wave * 2 + tt;
            const _Float16* rp = act1 + (tname * 16 + l15) * ROWH + s * 8;
            v4f acc = {0.f, 0.f, 0.f, 0.f};
            acc = __builtin_amdgcn_mfma_f32_16x16x32_f16(wof[0], *(const v8h*)(rp),      acc, 0, 0, 0);
            acc = __builtin_amdgcn_mfma_f32_16x16x32_f16(wof[1], *(const v8h*)(rp + 32), acc, 0, 0, 0);
            acc = __builtin_amdgcn_mfma_f32_16x16x32_f16(wof[2], *(const v8h*)(rp + 64), acc, 0, 0, 0);
            acc = __builtin_amdgcn_mfma_f32_16x16x32_f16(wof[3], *(const v8h*)(rp + 96), acc, 0, 0, 0);
            if (s == 0) cbuf[tname * 16 + l15] = acc[0];
        }
        __syncthreads();                               // bar5: cbuf ready

        // ---- quadrature + envelope + chain rule (wave 0, lanes 0-15) ----
        if (wave == 0 && lane < 16) {
            int row = b * 16 + lane;
            if (row < N) {
                float ah = 0.5f * t;
                float vic = cbuf[192 + lane];
                float g1  = cbuf[208 + lane];
                float g2  = cbuf[224 + lane];
                float g3  = cbuf[240 + lane];
                float dsum = 0.f, ds1 = 0.f, ds2 = 0.f, ds3 = 0.f;
                const float wq[3] = {0.5555555555555556f, 0.8888888888888889f, 0.5555555555555556f};
                #pragma unroll
                for (int qq = 0; qq < 3; qq++) {
                    float w = wq[qq];
                    dsum += w * cbuf[qq * 64 + lane];
                    ds1  += w * cbuf[qq * 64 + 16 + lane];
                    ds2  += w * cbuf[qq * 64 + 32 + lane];
                    ds3  += w * cbuf[qq * 64 + 48 + lane];
                }
                float tcv  = (vic + bouti) + ah * (dsum + 2.0f * boutd);
                float dtcr = g1 + ah * ds1;
                float dtct = g2 + ah * ds2;
                float dtcp = g3 + ah * ds3;
                float pot = tcv * sEnv + Aan;
                float gx0 = sEnv * dtcr + tcv * dsdr + dAdr;
                float gx1 = sEnv * dtct;
                float gx2 = sEnv * dtcp;
                float ax = -(gx0 * xr + gx1 * dthx + gx2 * dphx);
                float ay = -(gx0 * yr + gx1 * dthy + gx2 * dphy);
                float az = -(gx0 * zr + gx1 * dthz);
                outPot[row] = pot;
                outAcc[row * 3 + 0] = ax;
                outAcc[row * 3 + 1] = ay;
                outAcc[row * 3 + 2] = az;
            }
        }
    }
}

extern "C" void kernel_launch(void* const* d_in, const int* in_sizes, int n_in,
                              void* d_out, int out_size, void* d_ws, size_t ws_size,
                              hipStream_t stream) {
    (void)n_in; (void)out_size;
    const float* tx     = (const float*)d_in[0];
    const float* dpWin  = (const float*)d_in[1];
    const float* dpBin  = (const float*)d_in[2];
    const float* dpWh   = (const float*)d_in[3];
    const float* dpBh   = (const float*)d_in[4];
    const float* dpWout = (const float*)d_in[5];
    const float* dpBout = (const float*)d_in[6];
    const float* icWin  = (const float*)d_in[7];
    const float* icBin  = (const float*)d_in[8];
    const float* icWh   = (const float*)d_in[9];
    const float* icBh   = (const float*)d_in[10];
    const float* icWout = (const float*)d_in[11];
    const float* icBout = (const float*)d_in[12];

    int N = in_sizes[0] / 4;
    if (ws_size < (size_t)(106496 * sizeof(_Float16))) return;
    _Float16* pack = (_Float16*)d_ws;
    float* outPot = (float*)d_out;
    float* outAcc = outPot + N;

    pack_weights<<<(106496 + 255) / 256, 256, 0, stream>>>(dpWh, icWh, dpWin, icWin, pack);

    (void)hipFuncSetAttribute(reinterpret_cast<const void*>(node_main),
                              hipFuncAttributeMaxDynamicSharedMemorySize, SMEM_BYTES);
    node_main<<<256, 512, SMEM_BYTES, stream>>>(tx,
        dpBin, dpBh, dpWout, dpBout,
        icBin, icBh, icWout, icBout,
        pack, outPot, outAcc, N);
}